// Round 2
// baseline (523.746 us; speedup 1.0000x reference)
//
#include <hip/hip_runtime.h>
#include <stdint.h>

#define HD 1024
#define SEQ 2048
#define NC 32

typedef __bf16 bf16x4 __attribute__((ext_vector_type(4)));
typedef __bf16 bf16x8 __attribute__((ext_vector_type(8)));
typedef float f32x4 __attribute__((ext_vector_type(4)));

__device__ inline unsigned short f2bf(float f) {
  union { float f; unsigned int u; } v; v.f = f;
  unsigned int r = v.u + 0x7fffu + ((v.u >> 16) & 1u);
  return (unsigned short)(r >> 16);
}
__device__ inline unsigned int pk2bf(float a, float b) {
  return (unsigned int)f2bf(a) | ((unsigned int)f2bf(b) << 16);
}
__device__ inline bf16x8 ld_frag8(const unsigned short* p) {
  bf16x4 lo = *(const bf16x4*)p;
  bf16x4 hi = *(const bf16x4*)(p + 4);
  return __builtin_shufflevector(lo, hi, 0, 1, 2, 3, 4, 5, 6, 7);
}
// async 16B global->LDS (wave-uniform base + lane*16; LDS dest stays LINEAR)
__device__ inline void glds16(const unsigned short* g, unsigned short* l) {
  __builtin_amdgcn_global_load_lds(
      (const __attribute__((address_space(1))) unsigned int*)g,
      (__attribute__((address_space(3))) unsigned int*)l, 16, 0, 0);
}
// bijective XCD swizzle: requires gridDim.x == 8 and total % 8 == 0.
__device__ inline int2 swz_bid() {
  int lin = blockIdx.y * 8 + blockIdx.x;
  int s = (lin & 7) * (int)gridDim.y + (lin >> 3);
  return make_int2(s & 7, s >> 3);
}
// ---- T2 LDS swizzle (16B-chunk units). Tile = 128 rows x 32 bf16 cols = 512 chunks.
// logical chunk lc (= row*4 + colchunk) lives at physical chunk pc = lc ^ (row & 7).
// Bank check: rows 0..7 at fixed colchunk hit 8 distinct 16B slots -> 2 lanes/bank = free.
// inverse (physical -> logical), for pre-swizzling the global source of linear writes:
__device__ inline int inv_swz(int pc) {
  int b2 = (pc >> 2) & 1, b3 = (pc >> 3) & 1, b4 = (pc >> 4) & 1;
  return pc ^ (b2 ^ b4) ^ (b3 << 1) ^ (b4 << 2);
}
// swizzled read offset (in shorts) for logical (row, 16B-colchunk lq)
__device__ inline int swz_rd(int row, int lq) {
  return (((row << 2) | lq) ^ (row & 7)) << 3;
}

// ---------------- zero rows s<63 of output (fp32) ----------------
__global__ __launch_bounds__(256) void zero_head_kernel(float* __restrict__ out) {
  int i = (blockIdx.x * 256 + threadIdx.x) * 4;
  int b = i / 64512;
  int r = i - b * 64512;
  *(float4*)(out + (size_t)b * (SEQ * HD) + r) = make_float4(0.f, 0.f, 0.f, 0.f);
}

// ---------------- fp32 -> bf16 streaming convert (weights only now) ----------------
__global__ __launch_bounds__(256) void cvt_kernel(const float* __restrict__ in,
                                                  unsigned short* __restrict__ out, int n8) {
  int i = blockIdx.x * 256 + threadIdx.x;
  if (i < n8) {
    float4 a = ((const float4*)in)[(size_t)i * 2];
    float4 b = ((const float4*)in)[(size_t)i * 2 + 1];
    ((uint4*)out)[i] = make_uint4(pk2bf(a.x, a.y), pk2bf(a.z, a.w),
                                  pk2bf(b.x, b.y), pk2bf(b.z, b.w));
  }
}

// ---------------- query remap+pad -> bf16 (8192 x 1024) ----------------
__global__ __launch_bounds__(256) void cvt_q_kernel(const float* __restrict__ q,
                                                    unsigned short* __restrict__ out) {
  int i = blockIdx.x * 256 + threadIdx.x;  // [0, 8192*128)
  int g = i >> 7, c8 = (i & 127) * 8;
  int b = g >> 11, tt = g & 2047;
  uint4 o = make_uint4(0, 0, 0, 0);
  if (tt < 1985) {
    const float* src = q + ((size_t)(b << 11) + tt + 63) * HD + c8;
    float4 a = *(const float4*)src;
    float4 bb = *(const float4*)(src + 4);
    o = make_uint4(pk2bf(a.x, a.y), pk2bf(a.z, a.w), pk2bf(bb.x, bb.y), pk2bf(bb.z, bb.w));
  }
  *(uint4*)(out + (size_t)g * HD + c8) = o;
}

// ---------------- Q GEMM (bf16 A via glds, dbuf pipeline + swizzled LDS) ----------------
__global__ __launch_bounds__(256, 2) void gemm_q_kernel(
    const unsigned short* __restrict__ A, const unsigned short* __restrict__ W,
    const float* __restrict__ bias, unsigned short* __restrict__ Cout) {
  __shared__ unsigned short lds_a[2][4096];
  __shared__ unsigned short lds_b[2][4096];
  const int t = threadIdx.x;
  const int l = t & 63, w = t >> 6;
  const int wm = w >> 1, wn = w & 1;
  const int lr = l & 15, lq = l >> 4;
  const int2 bid = swz_bid();
  const size_t arow0 = (size_t)bid.y * 128;
  const size_t brow0 = (size_t)bid.x * 128;
  const int lc = inv_swz(t);          // logical chunk held by physical chunk t
  const int r0 = lc >> 2, c8 = (lc & 3) * 8;
  const unsigned short* a0 = A + (arow0 + r0) * HD + c8;
  const unsigned short* a1 = a0 + 64 * HD;   // physical chunk 256+t -> logical +256
  const unsigned short* b0 = W + (brow0 + r0) * HD + c8;
  const unsigned short* b1 = b0 + 64 * HD;

  f32x4 acc[4][4];
  for (int i = 0; i < 4; i++)
    for (int j = 0; j < 4; j++) acc[i][j] = (f32x4){0.f, 0.f, 0.f, 0.f};

  auto stage = [&](int buf, int k0) {
    glds16(a0 + k0, lds_a[buf] + t * 8);
    glds16(a1 + k0, lds_a[buf] + 2048 + t * 8);
    glds16(b0 + k0, lds_b[buf] + t * 8);
    glds16(b1 + k0, lds_b[buf] + 2048 + t * 8);
  };
  auto compute = [&](int buf) {
    bf16x8 af[4], bfr[4];
    for (int mt = 0; mt < 4; ++mt)
      af[mt] = *(const bf16x8*)(lds_a[buf] + swz_rd(wm * 64 + mt * 16 + lr, lq));
    for (int nt = 0; nt < 4; ++nt)
      bfr[nt] = *(const bf16x8*)(lds_b[buf] + swz_rd(wn * 64 + nt * 16 + lr, lq));
    for (int mt = 0; mt < 4; ++mt)
      for (int nt = 0; nt < 4; ++nt)
        acc[mt][nt] = __builtin_amdgcn_mfma_f32_16x16x32_bf16(af[mt], bfr[nt], acc[mt][nt], 0, 0, 0);
  };

  stage(0, 0);
  __syncthreads();
  for (int kk = 0; kk < 31; ++kk) {
    stage((kk & 1) ^ 1, (kk + 1) * 32);  // async loads in flight across the MFMA below
    compute(kk & 1);
    __syncthreads();                     // single barrier per K-step (drains vm+lgkm)
  }
  compute(1);

  for (int nt = 0; nt < 4; ++nt) {
    int n = bid.x * 128 + wn * 64 + nt * 16 + lr;
    float bvv = bias[n];
    for (int mt = 0; mt < 4; ++mt) {
      size_t mbase = arow0 + wm * 64 + mt * 16 + lq * 4;
      for (int r = 0; r < 4; ++r)
        Cout[(mbase + r) * HD + n] = f2bf(acc[mt][nt][r] + bvv);
    }
  }
}

// ---------------- fused K+V GEMM: fp32 A (reg-staged cvt), dbuf pipeline + swizzle ----------------
__global__ __launch_bounds__(256, 2) void gemm_kv_kernel(
    const float* __restrict__ A, const unsigned short* __restrict__ Wk,
    const unsigned short* __restrict__ Wv, const float* __restrict__ bk,
    const float* __restrict__ bv, unsigned short* __restrict__ Kout,
    unsigned short* __restrict__ Vt) {
  __shared__ unsigned short lds_a[2][4096];
  __shared__ unsigned short lds_k[2][4096];
  __shared__ unsigned short lds_v[2][4096];
  const int t = threadIdx.x;
  const int l = t & 63, w = t >> 6;
  const int wm = w >> 1, wn = w & 1;
  const int lr = l & 15, lq = l >> 4;
  const int2 bid = swz_bid();
  const size_t arow0 = (size_t)bid.y * 128;
  const size_t brow0 = (size_t)bid.x * 128;
  const int lc = inv_swz(t);
  const int r0 = lc >> 2, c8 = (lc & 3) * 8;
  const float* aF0 = A + (arow0 + r0) * HD + c8;        // fp32 source, pre-swizzled row/col
  const float* aF1 = aF0 + (size_t)64 * HD;
  const unsigned short* kp0 = Wk + (brow0 + r0) * HD + c8;
  const unsigned short* kp1 = kp0 + 64 * HD;
  const unsigned short* vp0 = Wv + (brow0 + r0) * HD + c8;
  const unsigned short* vp1 = vp0 + 64 * HD;

  f32x4 acck[4][4], accv[4][4];
  for (int i = 0; i < 4; i++)
    for (int j = 0; j < 4; j++) {
      acck[i][j] = (f32x4){0.f, 0.f, 0.f, 0.f};
      accv[i][j] = (f32x4){0.f, 0.f, 0.f, 0.f};
    }

  float4 fa0, fa1, fb0, fb1;  // staged fp32 A for the next tile
  auto loadA = [&](int k0) {
    fa0 = *(const float4*)(aF0 + k0); fa1 = *(const float4*)(aF0 + k0 + 4);
    fb0 = *(const float4*)(aF1 + k0); fb1 = *(const float4*)(aF1 + k0 + 4);
  };
  auto gldsW = [&](int buf, int k0) {
    glds16(kp0 + k0, lds_k[buf] + t * 8);
    glds16(kp1 + k0, lds_k[buf] + 2048 + t * 8);
    glds16(vp0 + k0, lds_v[buf] + t * 8);
    glds16(vp1 + k0, lds_v[buf] + 2048 + t * 8);
  };
  auto writeA = [&](int buf) {  // linear physical chunks t and 256+t: conflict-free b128 writes
    *(uint4*)(lds_a[buf] + t * 8) =
        make_uint4(pk2bf(fa0.x, fa0.y), pk2bf(fa0.z, fa0.w), pk2bf(fa1.x, fa1.y), pk2bf(fa1.z, fa1.w));
    *(uint4*)(lds_a[buf] + 2048 + t * 8) =
        make_uint4(pk2bf(fb0.x, fb0.y), pk2bf(fb0.z, fb0.w), pk2bf(fb1.x, fb1.y), pk2bf(fb1.z, fb1.w));
  };
  auto compute = [&](int buf) {
    bf16x8 af[4];
    for (int mt = 0; mt < 4; ++mt)
      af[mt] = *(const bf16x8*)(lds_a[buf] + swz_rd(wm * 64 + mt * 16 + lr, lq));
    {
      bf16x8 bfr[4];
      for (int nt = 0; nt < 4; ++nt)
        bfr[nt] = *(const bf16x8*)(lds_k[buf] + swz_rd(wn * 64 + nt * 16 + lr, lq));
      for (int mt = 0; mt < 4; ++mt)
        for (int nt = 0; nt < 4; ++nt)
          acck[mt][nt] = __builtin_amdgcn_mfma_f32_16x16x32_bf16(af[mt], bfr[nt], acck[mt][nt], 0, 0, 0);
    }
    {
      bf16x8 bfr[4];
      for (int nt = 0; nt < 4; ++nt)
        bfr[nt] = *(const bf16x8*)(lds_v[buf] + swz_rd(wn * 64 + nt * 16 + lr, lq));
      for (int mt = 0; mt < 4; ++mt)
        for (int nt = 0; nt < 4; ++nt)
          accv[mt][nt] = __builtin_amdgcn_mfma_f32_16x16x32_bf16(af[mt], bfr[nt], accv[mt][nt], 0, 0, 0);
    }
  };

  loadA(0); gldsW(0, 0); writeA(0);
  __syncthreads();
  for (int kk = 0; kk < 31; ++kk) {
    const int cur = kk & 1;
    const int k0n = (kk + 1) * 32;
    loadA(k0n);            // fp32 loads in flight across MFMA
    gldsW(cur ^ 1, k0n);   // glds in flight across MFMA
    compute(cur);
    writeA(cur ^ 1);       // waits only on the fp32 loads (oldest in vm queue)
    __syncthreads();       // single barrier per K-step: next tile ready, prior reads done
  }
  compute(1);

  // K store (row-major bf16)
  for (int nt = 0; nt < 4; ++nt) {
    int n = bid.x * 128 + wn * 64 + nt * 16 + lr;
    float bvv = bk[n];
    for (int mt = 0; mt < 4; ++mt) {
      size_t mbase = arow0 + wm * 64 + mt * 16 + lq * 4;
      for (int r = 0; r < 4; ++r)
        Kout[(mbase + r) * HD + n] = f2bf(acck[mt][nt][r] + bvv);
    }
  }
  // V store (transposed per (bc,head) layout for the attention PV step)
  for (int nt = 0; nt < 4; ++nt) {
    int n = bid.x * 128 + wn * 64 + nt * 16 + lr;
    float bvv = bv[n];
    int h = n >> 6, d = n & 63;
    for (int mt = 0; mt < 4; ++mt) {
      size_t m0 = arow0 + wm * 64 + mt * 16 + lq * 4;
      size_t bc = m0 >> 8, j = m0 & 255;
      *(ushort4*)(Vt + ((bc * 16 + h) * 64 + d) * 256 + j) =
          make_ushort4(f2bf(accv[mt][nt][0] + bvv), f2bf(accv[mt][nt][1] + bvv),
                       f2bf(accv[mt][nt][2] + bvv), f2bf(accv[mt][nt][3] + bvv));
    }
  }
}

// ---------------- fallback GEMM (fp32 in, register cvt staging) ----------------
__global__ __launch_bounds__(256, 2) void gemm_f32_kernel(
    const float* __restrict__ A, const float* __restrict__ W,
    const float* __restrict__ bias, unsigned short* __restrict__ Cout,
    int store_vt, int qremap) {
  __shared__ unsigned short lds_a[128 * 32];
  __shared__ unsigned short lds_b[128 * 32];
  const int t = threadIdx.x;
  const int l = t & 63, w = t >> 6;
  const int wm = w >> 1, wn = w & 1;
  const int lr = l & 15, lq = l >> 4;
  const size_t arow0 = (size_t)blockIdx.y * 128;
  const size_t brow0 = (size_t)blockIdx.x * 128;

  f32x4 acc[4][4];
  for (int i = 0; i < 4; i++)
    for (int j = 0; j < 4; j++) acc[i][j] = (f32x4){0.f, 0.f, 0.f, 0.f};

  for (int kk = 0; kk < 32; ++kk) {
    const int k0 = kk * 32;
    uint4 av[2], bv[2];
    for (int p = 0; p < 2; ++p) {
      int chunk = p * 256 + t;
      int row = chunk >> 2, c8 = (chunk & 3) * 8;
      size_t grow = arow0 + row;
      bool valid = true;
      const float* srcA;
      if (qremap) {
        int bb = (int)(grow >> 11), tt = (int)(grow & 2047);
        valid = tt < 1985;
        srcA = A + ((size_t)(bb << 11) + tt + 63) * HD + k0 + c8;
      } else {
        srcA = A + grow * HD + k0 + c8;
      }
      if (valid) {
        float4 x = *(const float4*)srcA, y = *(const float4*)(srcA + 4);
        av[p] = make_uint4(pk2bf(x.x, x.y), pk2bf(x.z, x.w), pk2bf(y.x, y.y), pk2bf(y.z, y.w));
      } else av[p] = make_uint4(0, 0, 0, 0);
      const float* srcB = W + (brow0 + row) * HD + k0 + c8;
      float4 x = *(const float4*)srcB, y = *(const float4*)(srcB + 4);
      bv[p] = make_uint4(pk2bf(x.x, x.y), pk2bf(x.z, x.w), pk2bf(y.x, y.y), pk2bf(y.z, y.w));
    }
    __syncthreads();
    for (int p = 0; p < 2; ++p) {
      int chunk = p * 256 + t;
      *(uint4*)(lds_a + chunk * 8) = av[p];
      *(uint4*)(lds_b + chunk * 8) = bv[p];
    }
    __syncthreads();
    bf16x8 af[4], bfr[4];
    for (int mt = 0; mt < 4; ++mt)
      af[mt] = *(const bf16x8*)(lds_a + (wm * 64 + mt * 16 + lr) * 32 + lq * 8);
    for (int nt = 0; nt < 4; ++nt)
      bfr[nt] = *(const bf16x8*)(lds_b + (wn * 64 + nt * 16 + lr) * 32 + lq * 8);
    for (int mt = 0; mt < 4; ++mt)
      for (int nt = 0; nt < 4; ++nt)
        acc[mt][nt] = __builtin_amdgcn_mfma_f32_16x16x32_bf16(af[mt], bfr[nt], acc[mt][nt], 0, 0, 0);
  }

  if (!store_vt) {
    for (int nt = 0; nt < 4; ++nt) {
      int n = blockIdx.x * 128 + wn * 64 + nt * 16 + lr;
      float bvv = bias[n];
      for (int mt = 0; mt < 4; ++mt) {
        size_t mbase = arow0 + wm * 64 + mt * 16 + lq * 4;
        for (int r = 0; r < 4; ++r)
          Cout[(mbase + r) * HD + n] = f2bf(acc[mt][nt][r] + bvv);
      }
    }
  } else {
    for (int nt = 0; nt < 4; ++nt) {
      int n = blockIdx.x * 128 + wn * 64 + nt * 16 + lr;
      float bvv = bias[n];
      int h = n >> 6, d = n & 63;
      for (int mt = 0; mt < 4; ++mt) {
        size_t m0 = arow0 + wm * 64 + mt * 16 + lq * 4;
        size_t bc = m0 >> 8, j = m0 & 255;
        *(ushort4*)(Cout + ((bc * 16 + h) * 64 + d) * 256 + j) =
            make_ushort4(f2bf(acc[mt][nt][0] + bvv), f2bf(acc[mt][nt][1] + bvv),
                         f2bf(acc[mt][nt][2] + bvv), f2bf(acc[mt][nt][3] + bvv));
      }
    }
  }
}

// ---------------- fused attention per (b, c, head); V read direct from Vt ----------------
#define QK_STRIDE 72
#define P_STRIDE 260

__global__ __launch_bounds__(256, 3) void attn_kernel(
    const unsigned short* __restrict__ Qp, const unsigned short* __restrict__ Kp,
    const unsigned short* __restrict__ Vt, float* __restrict__ out) {
  __shared__ unsigned short q_s[64 * QK_STRIDE];    // 9216 B
  __shared__ unsigned short k_s[256 * QK_STRIDE];   // 36864 B; P overlay 64x260 fits
  const int t = threadIdx.x;
  const int l = t & 63, w = t >> 6;
  const int lr = l & 15, lq = l >> 4;
  const int bid = blockIdx.x;
  const int head = bid & 15, cc = (bid >> 4) & 31, b = bid >> 9;
  const size_t qrow0 = (size_t)(b * NC + cc) * 64;
  const size_t kvrow0 = (size_t)(b * NC + cc) * 256;
  const int hcol = head * 64;
  const unsigned short* vbase = Vt + ((size_t)((b * NC + cc) * 16 + head) * 64) * 256;

  for (int p = 0; p < 2; ++p) {
    int chunk = p * 256 + t;
    int row = chunk >> 3, c8 = (chunk & 7) * 8;
    *(uint4*)(q_s + row * QK_STRIDE + c8) = *(const uint4*)(Qp + (qrow0 + row) * HD + hcol + c8);
  }
  for (int p = 0; p < 8; ++p) {
    int chunk = p * 256 + t;
    int row = chunk >> 3, c8 = (chunk & 7) * 8;
    *(uint4*)(k_s + row * QK_STRIDE + c8) = *(const uint4*)(Kp + (kvrow0 + row) * HD + hcol + c8);
  }
  __syncthreads();

  bf16x8 qa0 = ld_frag8(q_s + (w * 16 + lr) * QK_STRIDE + lq * 8);
  bf16x8 qa1 = ld_frag8(q_s + (w * 16 + lr) * QK_STRIDE + 32 + lq * 8);
  f32x4 sc[16];
  for (int nt = 0; nt < 16; ++nt) {
    bf16x8 kb0 = ld_frag8(k_s + (nt * 16 + lr) * QK_STRIDE + lq * 8);
    bf16x8 kb1 = ld_frag8(k_s + (nt * 16 + lr) * QK_STRIDE + 32 + lq * 8);
    f32x4 a = (f32x4){0.f, 0.f, 0.f, 0.f};
    a = __builtin_amdgcn_mfma_f32_16x16x32_bf16(qa0, kb0, a, 0, 0, 0);
    a = __builtin_amdgcn_mfma_f32_16x16x32_bf16(qa1, kb1, a, 0, 0, 0);
    sc[nt] = a;
  }
  float mrow[4] = {-1e30f, -1e30f, -1e30f, -1e30f};
  for (int nt = 0; nt < 16; ++nt)
    for (int r = 0; r < 4; ++r) mrow[r] = fmaxf(mrow[r], sc[nt][r]);
  for (int off = 1; off < 16; off <<= 1)
    for (int r = 0; r < 4; ++r) mrow[r] = fmaxf(mrow[r], __shfl_xor(mrow[r], off, 16));
  float srow[4] = {0.f, 0.f, 0.f, 0.f};
  const float cexp = 0.18033688011112042f;  // log2(e)/8
  for (int nt = 0; nt < 16; ++nt)
    for (int r = 0; r < 4; ++r) {
      float p = exp2f((sc[nt][r] - mrow[r]) * cexp);
      sc[nt][r] = p;
      srow[r] += p;
    }
  for (int off = 1; off < 16; off <<= 1)
    for (int r = 0; r < 4; ++r) srow[r] += __shfl_xor(srow[r], off, 16);

  __syncthreads();  // all waves done reading k_s -> reuse as P

  for (int nt = 0; nt < 16; ++nt)
    for (int r = 0; r < 4; ++r)
      k_s[(w * 16 + lq * 4 + r) * P_STRIDE + nt * 16 + lr] = f2bf(sc[nt][r]);

  f32x4 o[4];
  for (int i = 0; i < 4; ++i) o[i] = (f32x4){0.f, 0.f, 0.f, 0.f};
  for (int ks = 0; ks < 8; ++ks) {
    bf16x8 pa = ld_frag8(k_s + (w * 16 + lr) * P_STRIDE + ks * 32 + lq * 8);
    for (int nt2 = 0; nt2 < 4; ++nt2) {
      bf16x8 vb = *(const bf16x8*)(vbase + (size_t)(nt2 * 16 + lr) * 256 + ks * 32 + lq * 8);
      o[nt2] = __builtin_amdgcn_mfma_f32_16x16x32_bf16(pa, vb, o[nt2], 0, 0, 0);
    }
  }

  for (int r = 0; r < 4; ++r) {
    int strip = w * 16 + lq * 4 + r;
    int trow = cc * 64 + strip;
    if (trow < 1985) {
      size_t orow = (size_t)b * SEQ + trow + 63;
      float inv = 1.0f / srow[r];
      for (int nt2 = 0; nt2 < 4; ++nt2)
        out[orow * HD + hcol + nt2 * 16 + lr] = o[nt2][r] * inv;
    }
  }
}

extern "C" void kernel_launch(void* const* d_in, const int* in_sizes, int n_in,
                              void* d_out, int out_size, void* d_ws, size_t ws_size,
                              hipStream_t stream) {
  (void)in_sizes; (void)n_in; (void)out_size;
  const float* query = (const float*)d_in[0];
  const float* kv    = (const float*)d_in[1];
  const float* Wq    = (const float*)d_in[2];
  const float* bq    = (const float*)d_in[3];
  const float* Wk    = (const float*)d_in[4];
  const float* bk    = (const float*)d_in[5];
  const float* Wv    = (const float*)d_in[6];
  const float* bv    = (const float*)d_in[7];
  float* out = (float*)d_out;

  unsigned short* Qp  = (unsigned short*)d_ws;          // 8192x1024
  unsigned short* Kp  = Qp + (size_t)8192 * 1024;       // 32768x1024
  unsigned short* Vt  = Kp + (size_t)32768 * 1024;      // 32768x1024 (transposed layout)
  unsigned short* Qbf = Vt + (size_t)32768 * 1024;      // 8192x1024
  unsigned short* KVb = Qbf + (size_t)8192 * 1024;      // (unused now, kept for layout)
  unsigned short* Wqb = KVb + (size_t)32768 * 1024;     // 1024x1024
  unsigned short* Wkb = Wqb + (size_t)1024 * 1024;
  unsigned short* Wvb = Wkb + (size_t)1024 * 1024;
  const size_t need = ((size_t)8192 * 1024 * 2 + (size_t)32768 * 1024 * 2 + (size_t)1024 * 1024 * 3) * 2;
  const bool big = ws_size >= need;

  zero_head_kernel<<<dim3(252), dim3(256), 0, stream>>>(out);
  if (big) {
    cvt_q_kernel<<<dim3(4096), dim3(256), 0, stream>>>(query, Qbf);
    cvt_kernel<<<dim3(512), dim3(256), 0, stream>>>(Wq, Wqb, 131072);
    cvt_kernel<<<dim3(512), dim3(256), 0, stream>>>(Wk, Wkb, 131072);
    cvt_kernel<<<dim3(512), dim3(256), 0, stream>>>(Wv, Wvb, 131072);
    gemm_q_kernel<<<dim3(8, 64), dim3(256), 0, stream>>>(Qbf, Wqb, bq, Qp);
    gemm_kv_kernel<<<dim3(8, 256), dim3(256), 0, stream>>>(kv, Wkb, Wvb, bk, bv, Kp, Vt);
  } else {
    gemm_f32_kernel<<<dim3(8, 64), dim3(256), 0, stream>>>(query, Wq, bq, Qp, 0, 1);
    gemm_f32_kernel<<<dim3(8, 256), dim3(256), 0, stream>>>(kv, Wk, bk, Kp, 0, 0);
    gemm_f32_kernel<<<dim3(8, 256), dim3(256), 0, stream>>>(kv, Wv, bv, Vt, 1, 0);
  }
  attn_kernel<<<dim3(2048), dim3(256), 0, stream>>>(Qp, Kp, Vt, out);
}

// Round 3
// 461.543 us; speedup vs baseline: 1.1348x; 1.1348x over previous
//
#include <hip/hip_runtime.h>
#include <stdint.h>

#define HD 1024
#define SEQ 2048
#define NC 32

typedef __bf16 bf16x4 __attribute__((ext_vector_type(4)));
typedef __bf16 bf16x8 __attribute__((ext_vector_type(8)));
typedef float f32x4 __attribute__((ext_vector_type(4)));

__device__ inline unsigned short f2bf(float f) {
  union { float f; unsigned int u; } v; v.f = f;
  unsigned int r = v.u + 0x7fffu + ((v.u >> 16) & 1u);
  return (unsigned short)(r >> 16);
}
__device__ inline unsigned int pk2bf(float a, float b) {
  return (unsigned int)f2bf(a) | ((unsigned int)f2bf(b) << 16);
}
__device__ inline bf16x8 ld_frag8(const unsigned short* p) {
  bf16x4 lo = *(const bf16x4*)p;
  bf16x4 hi = *(const bf16x4*)(p + 4);
  return __builtin_shufflevector(lo, hi, 0, 1, 2, 3, 4, 5, 6, 7);
}
// async 16B global->LDS (wave-uniform base + lane*16; LDS dest stays LINEAR)
__device__ inline void glds16(const unsigned short* g, unsigned short* l) {
  __builtin_amdgcn_global_load_lds(
      (const __attribute__((address_space(1))) unsigned int*)g,
      (__attribute__((address_space(3))) unsigned int*)l, 16, 0, 0);
}
// bijective XCD swizzle: requires gridDim.x == 8 and total % 8 == 0.
__device__ inline int2 swz_bid() {
  int lin = blockIdx.y * 8 + blockIdx.x;
  int s = (lin & 7) * (int)gridDim.y + (lin >> 3);
  return make_int2(s & 7, s >> 3);
}
// ---- 128x64 bf16 tile swizzle: 8 col-chunks (16B) per row; involutive per-row XOR.
// physical chunk = (row<<3) | (colchunk ^ (row&7)); read offset in shorts:
__device__ inline int swz64(int row, int j) { return (row * 8 + (j ^ (row & 7))) * 8; }

// ---------------- zero rows s<63 of output (fallback path only) ----------------
__global__ __launch_bounds__(256) void zero_head_kernel(float* __restrict__ out) {
  int i = (blockIdx.x * 256 + threadIdx.x) * 4;
  int b = i / 64512;
  int r = i - b * 64512;
  *(float4*)(out + (size_t)b * (SEQ * HD) + r) = make_float4(0.f, 0.f, 0.f, 0.f);
}

// ---------------- merged: zero head rows + query remap/pad -> bf16 ----------------
__global__ __launch_bounds__(256) void prep_q_kernel(const float* __restrict__ q,
                                                     unsigned short* __restrict__ out,
                                                     float* __restrict__ oz) {
  int bid = blockIdx.x;
  if (bid < 252) {  // zero out[b, 0:63, :]
    int i = (bid * 256 + threadIdx.x) * 4;
    int b = i / 64512;
    int r = i - b * 64512;
    *(float4*)(oz + (size_t)b * (SEQ * HD) + r) = make_float4(0.f, 0.f, 0.f, 0.f);
    return;
  }
  int i = (bid - 252) * 256 + threadIdx.x;  // [0, 8192*128)
  int g = i >> 7, c8 = (i & 127) * 8;
  int b = g >> 11, tt = g & 2047;
  uint4 o = make_uint4(0, 0, 0, 0);
  if (tt < 1985) {
    const float* src = q + ((size_t)(b << 11) + tt + 63) * HD + c8;
    float4 a = *(const float4*)src;
    float4 bb = *(const float4*)(src + 4);
    o = make_uint4(pk2bf(a.x, a.y), pk2bf(a.z, a.w), pk2bf(bb.x, bb.y), pk2bf(bb.z, bb.w));
  }
  *(uint4*)(out + (size_t)g * HD + c8) = o;
}

// ---------------- fp32 -> bf16 streaming convert (kv tensor) ----------------
__global__ __launch_bounds__(256) void cvt_kernel(const float* __restrict__ in,
                                                  unsigned short* __restrict__ out, int n8) {
  int i = blockIdx.x * 256 + threadIdx.x;
  if (i < n8) {
    float4 a = ((const float4*)in)[(size_t)i * 2];
    float4 b = ((const float4*)in)[(size_t)i * 2 + 1];
    ((uint4*)out)[i] = make_uint4(pk2bf(a.x, a.y), pk2bf(a.z, a.w),
                                  pk2bf(b.x, b.y), pk2bf(b.z, b.w));
  }
}

// ---------------- all 3 weight matrices -> bf16 in one dispatch ----------------
__global__ __launch_bounds__(256) void cvt_w3_kernel(const float* __restrict__ Wq,
                                                     const float* __restrict__ Wk,
                                                     const float* __restrict__ Wv,
                                                     unsigned short* __restrict__ dst) {
  int bid = blockIdx.x;              // [0, 1536)
  int which = bid >> 9;              // 512 blocks per matrix
  int i = (bid & 511) * 256 + threadIdx.x;  // [0, 131072)
  const float* src = which == 0 ? Wq : (which == 1 ? Wk : Wv);
  float4 a = ((const float4*)src)[(size_t)i * 2];
  float4 b = ((const float4*)src)[(size_t)i * 2 + 1];
  ((uint4*)(dst + (size_t)which * 1048576))[i] =
      make_uint4(pk2bf(a.x, a.y), pk2bf(a.z, a.w), pk2bf(b.x, b.y), pk2bf(b.z, b.w));
}

// ---------------- Q GEMM (bf16, glds, BK=64, swizzled LDS, 2 barriers/step) ----------------
__global__ __launch_bounds__(256, 2) void gemm_q_kernel(
    const unsigned short* __restrict__ A, const unsigned short* __restrict__ W,
    const float* __restrict__ bias, unsigned short* __restrict__ Cout) {
  __shared__ unsigned short lds_a[128 * 64];
  __shared__ unsigned short lds_b[128 * 64];
  const int t = threadIdx.x;
  const int l = t & 63, w = t >> 6;
  const int wm = w >> 1, wn = w & 1;
  const int lr = l & 15, lq = l >> 4;
  const int2 bid = swz_bid();
  const size_t arow0 = (size_t)bid.y * 128;
  const size_t brow0 = (size_t)bid.x * 128;
  // staging map: physical chunk pc = p*256+t -> logical (row, colchunk^(row&7))
  int pr[4], pco[4];
#pragma unroll
  for (int p = 0; p < 4; ++p) {
    int pc = p * 256 + t;
    pr[p] = pc >> 3;
    pco[p] = ((pc & 7) ^ (pr[p] & 7)) * 8;
  }

  f32x4 acc[4][4];
  for (int i = 0; i < 4; i++)
    for (int j = 0; j < 4; j++) acc[i][j] = (f32x4){0.f, 0.f, 0.f, 0.f};

  for (int kk = 0; kk < 16; ++kk) {
    const int k0 = kk * 64;
    __syncthreads();
#pragma unroll
    for (int p = 0; p < 4; ++p) {
      glds16(A + (arow0 + pr[p]) * HD + k0 + pco[p], lds_a + (p * 256 + t) * 8);
      glds16(W + (brow0 + pr[p]) * HD + k0 + pco[p], lds_b + (p * 256 + t) * 8);
    }
    __syncthreads();
#pragma unroll
    for (int h = 0; h < 2; ++h) {
      bf16x8 af[4], bfr[4];
      for (int mt = 0; mt < 4; ++mt)
        af[mt] = *(const bf16x8*)(lds_a + swz64(wm * 64 + mt * 16 + lr, h * 4 + lq));
      for (int nt = 0; nt < 4; ++nt)
        bfr[nt] = *(const bf16x8*)(lds_b + swz64(wn * 64 + nt * 16 + lr, h * 4 + lq));
      for (int mt = 0; mt < 4; ++mt)
        for (int nt = 0; nt < 4; ++nt)
          acc[mt][nt] = __builtin_amdgcn_mfma_f32_16x16x32_bf16(af[mt], bfr[nt], acc[mt][nt], 0, 0, 0);
    }
  }

  for (int nt = 0; nt < 4; ++nt) {
    int n = bid.x * 128 + wn * 64 + nt * 16 + lr;
    float bvv = bias[n];
    for (int mt = 0; mt < 4; ++mt) {
      size_t mbase = arow0 + wm * 64 + mt * 16 + lq * 4;
      for (int r = 0; r < 4; ++r)
        Cout[(mbase + r) * HD + n] = f2bf(acc[mt][nt][r] + bvv);
    }
  }
}

// ---------------- fused K+V GEMM (bf16 A, glds, BK=64, swizzled LDS, 2 barriers/step) ----------------
__global__ __launch_bounds__(256, 2) void gemm_kv_kernel(
    const unsigned short* __restrict__ A, const unsigned short* __restrict__ Wk,
    const unsigned short* __restrict__ Wv, const float* __restrict__ bk,
    const float* __restrict__ bv, unsigned short* __restrict__ Kout,
    unsigned short* __restrict__ Vt) {
  __shared__ unsigned short lds_a[128 * 64];
  __shared__ unsigned short lds_k[128 * 64];
  __shared__ unsigned short lds_v[128 * 64];
  const int t = threadIdx.x;
  const int l = t & 63, w = t >> 6;
  const int wm = w >> 1, wn = w & 1;
  const int lr = l & 15, lq = l >> 4;
  const int2 bid = swz_bid();
  const size_t arow0 = (size_t)bid.y * 128;
  const size_t brow0 = (size_t)bid.x * 128;
  int pr[4], pco[4];
#pragma unroll
  for (int p = 0; p < 4; ++p) {
    int pc = p * 256 + t;
    pr[p] = pc >> 3;
    pco[p] = ((pc & 7) ^ (pr[p] & 7)) * 8;
  }

  f32x4 acck[4][4], accv[4][4];
  for (int i = 0; i < 4; i++)
    for (int j = 0; j < 4; j++) {
      acck[i][j] = (f32x4){0.f, 0.f, 0.f, 0.f};
      accv[i][j] = (f32x4){0.f, 0.f, 0.f, 0.f};
    }

  for (int kk = 0; kk < 16; ++kk) {
    const int k0 = kk * 64;
    __syncthreads();
#pragma unroll
    for (int p = 0; p < 4; ++p) {
      glds16(A + (arow0 + pr[p]) * HD + k0 + pco[p], lds_a + (p * 256 + t) * 8);
      glds16(Wk + (brow0 + pr[p]) * HD + k0 + pco[p], lds_k + (p * 256 + t) * 8);
      glds16(Wv + (brow0 + pr[p]) * HD + k0 + pco[p], lds_v + (p * 256 + t) * 8);
    }
    __syncthreads();
#pragma unroll
    for (int h = 0; h < 2; ++h) {
      bf16x8 af[4];
      for (int mt = 0; mt < 4; ++mt)
        af[mt] = *(const bf16x8*)(lds_a + swz64(wm * 64 + mt * 16 + lr, h * 4 + lq));
      {
        bf16x8 bfr[4];
        for (int nt = 0; nt < 4; ++nt)
          bfr[nt] = *(const bf16x8*)(lds_k + swz64(wn * 64 + nt * 16 + lr, h * 4 + lq));
        for (int mt = 0; mt < 4; ++mt)
          for (int nt = 0; nt < 4; ++nt)
            acck[mt][nt] = __builtin_amdgcn_mfma_f32_16x16x32_bf16(af[mt], bfr[nt], acck[mt][nt], 0, 0, 0);
      }
      {
        bf16x8 bfr[4];
        for (int nt = 0; nt < 4; ++nt)
          bfr[nt] = *(const bf16x8*)(lds_v + swz64(wn * 64 + nt * 16 + lr, h * 4 + lq));
        for (int mt = 0; mt < 4; ++mt)
          for (int nt = 0; nt < 4; ++nt)
            accv[mt][nt] = __builtin_amdgcn_mfma_f32_16x16x32_bf16(af[mt], bfr[nt], accv[mt][nt], 0, 0, 0);
      }
    }
  }

  // K store (row-major bf16)
  for (int nt = 0; nt < 4; ++nt) {
    int n = bid.x * 128 + wn * 64 + nt * 16 + lr;
    float bvv = bk[n];
    for (int mt = 0; mt < 4; ++mt) {
      size_t mbase = arow0 + wm * 64 + mt * 16 + lq * 4;
      for (int r = 0; r < 4; ++r)
        Kout[(mbase + r) * HD + n] = f2bf(acck[mt][nt][r] + bvv);
    }
  }
  // V store (transposed per (bc,head) layout for the attention PV step)
  for (int nt = 0; nt < 4; ++nt) {
    int n = bid.x * 128 + wn * 64 + nt * 16 + lr;
    float bvv = bv[n];
    int h = n >> 6, d = n & 63;
    for (int mt = 0; mt < 4; ++mt) {
      size_t m0 = arow0 + wm * 64 + mt * 16 + lq * 4;
      size_t bc = m0 >> 8, j = m0 & 255;
      *(ushort4*)(Vt + ((bc * 16 + h) * 64 + d) * 256 + j) =
          make_ushort4(f2bf(accv[mt][nt][0] + bvv), f2bf(accv[mt][nt][1] + bvv),
                       f2bf(accv[mt][nt][2] + bvv), f2bf(accv[mt][nt][3] + bvv));
    }
  }
}

// ---------------- fallback GEMM (fp32 in, register cvt staging) ----------------
__global__ __launch_bounds__(256, 2) void gemm_f32_kernel(
    const float* __restrict__ A, const float* __restrict__ W,
    const float* __restrict__ bias, unsigned short* __restrict__ Cout,
    int store_vt, int qremap) {
  __shared__ unsigned short lds_a[128 * 32];
  __shared__ unsigned short lds_b[128 * 32];
  const int t = threadIdx.x;
  const int l = t & 63, w = t >> 6;
  const int wm = w >> 1, wn = w & 1;
  const int lr = l & 15, lq = l >> 4;
  const size_t arow0 = (size_t)blockIdx.y * 128;
  const size_t brow0 = (size_t)blockIdx.x * 128;

  f32x4 acc[4][4];
  for (int i = 0; i < 4; i++)
    for (int j = 0; j < 4; j++) acc[i][j] = (f32x4){0.f, 0.f, 0.f, 0.f};

  for (int kk = 0; kk < 32; ++kk) {
    const int k0 = kk * 32;
    uint4 av[2], bv[2];
    for (int p = 0; p < 2; ++p) {
      int chunk = p * 256 + t;
      int row = chunk >> 2, c8 = (chunk & 3) * 8;
      size_t grow = arow0 + row;
      bool valid = true;
      const float* srcA;
      if (qremap) {
        int bb = (int)(grow >> 11), tt = (int)(grow & 2047);
        valid = tt < 1985;
        srcA = A + ((size_t)(bb << 11) + tt + 63) * HD + k0 + c8;
      } else {
        srcA = A + grow * HD + k0 + c8;
      }
      if (valid) {
        float4 x = *(const float4*)srcA, y = *(const float4*)(srcA + 4);
        av[p] = make_uint4(pk2bf(x.x, x.y), pk2bf(x.z, x.w), pk2bf(y.x, y.y), pk2bf(y.z, y.w));
      } else av[p] = make_uint4(0, 0, 0, 0);
      const float* srcB = W + (brow0 + row) * HD + k0 + c8;
      float4 x = *(const float4*)srcB, y = *(const float4*)(srcB + 4);
      bv[p] = make_uint4(pk2bf(x.x, x.y), pk2bf(x.z, x.w), pk2bf(y.x, y.y), pk2bf(y.z, y.w));
    }
    __syncthreads();
    for (int p = 0; p < 2; ++p) {
      int chunk = p * 256 + t;
      *(uint4*)(lds_a + chunk * 8) = av[p];
      *(uint4*)(lds_b + chunk * 8) = bv[p];
    }
    __syncthreads();
    bf16x8 af[4], bfr[4];
    for (int mt = 0; mt < 4; ++mt)
      af[mt] = *(const bf16x8*)(lds_a + (wm * 64 + mt * 16 + lr) * 32 + lq * 8);
    for (int nt = 0; nt < 4; ++nt)
      bfr[nt] = *(const bf16x8*)(lds_b + (wn * 64 + nt * 16 + lr) * 32 + lq * 8);
    for (int mt = 0; mt < 4; ++mt)
      for (int nt = 0; nt < 4; ++nt)
        acc[mt][nt] = __builtin_amdgcn_mfma_f32_16x16x32_bf16(af[mt], bfr[nt], acc[mt][nt], 0, 0, 0);
  }

  if (!store_vt) {
    for (int nt = 0; nt < 4; ++nt) {
      int n = blockIdx.x * 128 + wn * 64 + nt * 16 + lr;
      float bvv = bias[n];
      for (int mt = 0; mt < 4; ++mt) {
        size_t mbase = arow0 + wm * 64 + mt * 16 + lq * 4;
        for (int r = 0; r < 4; ++r)
          Cout[(mbase + r) * HD + n] = f2bf(acc[mt][nt][r] + bvv);
      }
    }
  } else {
    for (int nt = 0; nt < 4; ++nt) {
      int n = blockIdx.x * 128 + wn * 64 + nt * 16 + lr;
      float bvv = bias[n];
      int h = n >> 6, d = n & 63;
      for (int mt = 0; mt < 4; ++mt) {
        size_t m0 = arow0 + wm * 64 + mt * 16 + lq * 4;
        size_t bc = m0 >> 8, j = m0 & 255;
        *(ushort4*)(Cout + ((bc * 16 + h) * 64 + d) * 256 + j) =
            make_ushort4(f2bf(acc[mt][nt][0] + bvv), f2bf(acc[mt][nt][1] + bvv),
                         f2bf(acc[mt][nt][2] + bvv), f2bf(acc[mt][nt][3] + bvv));
      }
    }
  }
}

// ---------------- fused attention per (b, c, head); V read direct from Vt ----------------
#define QK_STRIDE 72
#define P_STRIDE 260

__global__ __launch_bounds__(256, 3) void attn_kernel(
    const unsigned short* __restrict__ Qp, const unsigned short* __restrict__ Kp,
    const unsigned short* __restrict__ Vt, float* __restrict__ out) {
  __shared__ unsigned short q_s[64 * QK_STRIDE];    // 9216 B
  __shared__ unsigned short k_s[256 * QK_STRIDE];   // 36864 B; P overlay 64x260 fits
  const int t = threadIdx.x;
  const int l = t & 63, w = t >> 6;
  const int lr = l & 15, lq = l >> 4;
  const int bid = blockIdx.x;
  const int head = bid & 15, cc = (bid >> 4) & 31, b = bid >> 9;
  const size_t qrow0 = (size_t)(b * NC + cc) * 64;
  const size_t kvrow0 = (size_t)(b * NC + cc) * 256;
  const int hcol = head * 64;
  const unsigned short* vbase = Vt + ((size_t)((b * NC + cc) * 16 + head) * 64) * 256;

  for (int p = 0; p < 2; ++p) {
    int chunk = p * 256 + t;
    int row = chunk >> 3, c8 = (chunk & 7) * 8;
    *(uint4*)(q_s + row * QK_STRIDE + c8) = *(const uint4*)(Qp + (qrow0 + row) * HD + hcol + c8);
  }
  for (int p = 0; p < 8; ++p) {
    int chunk = p * 256 + t;
    int row = chunk >> 3, c8 = (chunk & 7) * 8;
    *(uint4*)(k_s + row * QK_STRIDE + c8) = *(const uint4*)(Kp + (kvrow0 + row) * HD + hcol + c8);
  }
  __syncthreads();

  bf16x8 qa0 = ld_frag8(q_s + (w * 16 + lr) * QK_STRIDE + lq * 8);
  bf16x8 qa1 = ld_frag8(q_s + (w * 16 + lr) * QK_STRIDE + 32 + lq * 8);
  f32x4 sc[16];
  __builtin_amdgcn_s_setprio(1);
  for (int nt = 0; nt < 16; ++nt) {
    bf16x8 kb0 = ld_frag8(k_s + (nt * 16 + lr) * QK_STRIDE + lq * 8);
    bf16x8 kb1 = ld_frag8(k_s + (nt * 16 + lr) * QK_STRIDE + 32 + lq * 8);
    f32x4 a = (f32x4){0.f, 0.f, 0.f, 0.f};
    a = __builtin_amdgcn_mfma_f32_16x16x32_bf16(qa0, kb0, a, 0, 0, 0);
    a = __builtin_amdgcn_mfma_f32_16x16x32_bf16(qa1, kb1, a, 0, 0, 0);
    sc[nt] = a;
  }
  __builtin_amdgcn_s_setprio(0);
  float mrow[4] = {-1e30f, -1e30f, -1e30f, -1e30f};
  for (int nt = 0; nt < 16; ++nt)
    for (int r = 0; r < 4; ++r) mrow[r] = fmaxf(mrow[r], sc[nt][r]);
  for (int off = 1; off < 16; off <<= 1)
    for (int r = 0; r < 4; ++r) mrow[r] = fmaxf(mrow[r], __shfl_xor(mrow[r], off, 16));
  float srow[4] = {0.f, 0.f, 0.f, 0.f};
  const float cexp = 0.18033688011112042f;  // log2(e)/8
  for (int nt = 0; nt < 16; ++nt)
    for (int r = 0; r < 4; ++r) {
      float p = exp2f((sc[nt][r] - mrow[r]) * cexp);
      sc[nt][r] = p;
      srow[r] += p;
    }
  for (int off = 1; off < 16; off <<= 1)
    for (int r = 0; r < 4; ++r) srow[r] += __shfl_xor(srow[r], off, 16);

  // T14: issue V(ks=0) loads now; HBM latency hides under the barrier + P-writes below
  bf16x8 va[4];
#pragma unroll
  for (int nt2 = 0; nt2 < 4; ++nt2)
    va[nt2] = *(const bf16x8*)(vbase + (size_t)(nt2 * 16 + lr) * 256 + lq * 8);

  __syncthreads();  // all waves done reading k_s -> reuse as P

  for (int nt = 0; nt < 16; ++nt)
    for (int r = 0; r < 4; ++r)
      k_s[(w * 16 + lq * 4 + r) * P_STRIDE + nt * 16 + lr] = f2bf(sc[nt][r]);

  f32x4 o[4];
  for (int i = 0; i < 4; ++i) o[i] = (f32x4){0.f, 0.f, 0.f, 0.f};
  bf16x8 vbuf[4];
#pragma unroll
  for (int ks = 0; ks < 8; ks += 2) {
#pragma unroll
    for (int nt2 = 0; nt2 < 4; ++nt2)
      vbuf[nt2] = *(const bf16x8*)(vbase + (size_t)(nt2 * 16 + lr) * 256 + (ks + 1) * 32 + lq * 8);
    bf16x8 pa = ld_frag8(k_s + (w * 16 + lr) * P_STRIDE + ks * 32 + lq * 8);
    __builtin_amdgcn_s_setprio(1);
#pragma unroll
    for (int nt2 = 0; nt2 < 4; ++nt2)
      o[nt2] = __builtin_amdgcn_mfma_f32_16x16x32_bf16(pa, va[nt2], o[nt2], 0, 0, 0);
    __builtin_amdgcn_s_setprio(0);
    if (ks + 2 < 8) {
#pragma unroll
      for (int nt2 = 0; nt2 < 4; ++nt2)
        va[nt2] = *(const bf16x8*)(vbase + (size_t)(nt2 * 16 + lr) * 256 + (ks + 2) * 32 + lq * 8);
    }
    bf16x8 pb = ld_frag8(k_s + (w * 16 + lr) * P_STRIDE + (ks + 1) * 32 + lq * 8);
    __builtin_amdgcn_s_setprio(1);
#pragma unroll
    for (int nt2 = 0; nt2 < 4; ++nt2)
      o[nt2] = __builtin_amdgcn_mfma_f32_16x16x32_bf16(pb, vbuf[nt2], o[nt2], 0, 0, 0);
    __builtin_amdgcn_s_setprio(0);
  }

  for (int r = 0; r < 4; ++r) {
    int strip = w * 16 + lq * 4 + r;
    int trow = cc * 64 + strip;
    if (trow < 1985) {
      size_t orow = (size_t)b * SEQ + trow + 63;
      float inv = 1.0f / srow[r];
      for (int nt2 = 0; nt2 < 4; ++nt2)
        out[orow * HD + hcol + nt2 * 16 + lr] = o[nt2][r] * inv;
    }
  }
}

extern "C" void kernel_launch(void* const* d_in, const int* in_sizes, int n_in,
                              void* d_out, int out_size, void* d_ws, size_t ws_size,
                              hipStream_t stream) {
  (void)in_sizes; (void)n_in; (void)out_size;
  const float* query = (const float*)d_in[0];
  const float* kv    = (const float*)d_in[1];
  const float* Wq    = (const float*)d_in[2];
  const float* bq    = (const float*)d_in[3];
  const float* Wk    = (const float*)d_in[4];
  const float* bk    = (const float*)d_in[5];
  const float* Wv    = (const float*)d_in[6];
  const float* bv    = (const float*)d_in[7];
  float* out = (float*)d_out;

  unsigned short* Qp  = (unsigned short*)d_ws;          // 8192x1024
  unsigned short* Kp  = Qp + (size_t)8192 * 1024;       // 32768x1024
  unsigned short* Vt  = Kp + (size_t)32768 * 1024;      // 32768x1024 (transposed layout)
  unsigned short* Qbf = Vt + (size_t)32768 * 1024;      // 8192x1024
  unsigned short* KVb = Qbf + (size_t)8192 * 1024;      // 32768x1024
  unsigned short* Wqb = KVb + (size_t)32768 * 1024;     // 1024x1024 x3 (contiguous)
  const size_t need = ((size_t)8192 * 1024 * 2 + (size_t)32768 * 1024 * 2 + (size_t)1024 * 1024 * 3) * 2;
  const bool big = ws_size >= need;

  if (big) {
    prep_q_kernel<<<dim3(4348), dim3(256), 0, stream>>>(query, Qbf, out);
    cvt_w3_kernel<<<dim3(1536), dim3(256), 0, stream>>>(Wq, Wk, Wv, Wqb);
    cvt_kernel<<<dim3(16384), dim3(256), 0, stream>>>(kv, KVb, 4194304);
    gemm_q_kernel<<<dim3(8, 64), dim3(256), 0, stream>>>(Qbf, Wqb, bq, Qp);
    gemm_kv_kernel<<<dim3(8, 256), dim3(256), 0, stream>>>(KVb, Wqb + (size_t)1048576,
                                                           Wqb + (size_t)2097152, bk, bv, Kp, Vt);
  } else {
    zero_head_kernel<<<dim3(252), dim3(256), 0, stream>>>(out);
    gemm_f32_kernel<<<dim3(8, 64), dim3(256), 0, stream>>>(query, Wq, bq, Qp, 0, 1);
    gemm_f32_kernel<<<dim3(8, 256), dim3(256), 0, stream>>>(kv, Wk, bk, Kp, 0, 0);
    gemm_f32_kernel<<<dim3(8, 256), dim3(256), 0, stream>>>(kv, Wv, bv, Vt, 1, 0);
  }
  attn_kernel<<<dim3(2048), dim3(256), 0, stream>>>(Qp, Kp, Vt, out);
}